// Round 6
// baseline (206.391 us; speedup 1.0000x reference)
//
#include <hip/hip_runtime.h>

#define N_NODES 50000
#define N_EDGES 800000
#define D 128
#define NGROUPS 3125  // N_NODES / 16

typedef __attribute__((ext_vector_type(8))) short short8;
typedef __attribute__((ext_vector_type(4))) float f32x4;

__device__ __forceinline__ float bits2f(unsigned int u) {
    union { unsigned int u; float f; } c; c.u = u; return c.f;
}
__device__ __forceinline__ unsigned short f2b(float f) {
    union { float f; unsigned int u; } c; c.f = f;
    unsigned int r = c.u + 0x7fffu + ((c.u >> 16) & 1u);
    return (unsigned short)(r >> 16);
}

// ---------------- CSR build ----------------

__global__ void k_degrank(const int* __restrict__ dst, int* __restrict__ deg,
                          int* __restrict__ rank) {
    int e = blockIdx.x * blockDim.x + threadIdx.x;
    if (e < N_EDGES) rank[e] = atomicAdd(&deg[dst[e]], 1);
}

__global__ void k_scan1(const int* __restrict__ deg, int* __restrict__ rs,
                        int* __restrict__ bsum) {
    __shared__ int s[1024];
    int tid = threadIdx.x;
    int i = blockIdx.x * 1024 + tid;
    int v = (i < N_NODES) ? deg[i] : 0;
    s[tid] = v;
    __syncthreads();
    for (int off = 1; off < 1024; off <<= 1) {
        int t = (tid >= off) ? s[tid - off] : 0;
        __syncthreads();
        s[tid] += t;
        __syncthreads();
    }
    if (i < N_NODES) rs[i] = s[tid] - v;
    if (tid == 1023) bsum[blockIdx.x] = s[1023];
}

// single-wave shfl prefix scan over block sums (nb <= 64); uniform control,
// shuffles executed by all 64 lanes (guard only on the add).
__global__ void k_scan2(int* __restrict__ bsum, int nb) {
    int lane = threadIdx.x;
    int v = (lane < nb) ? bsum[lane] : 0;
    int s = v;
    #pragma unroll
    for (int off = 1; off < 64; off <<= 1) {
        int t = __shfl_up(s, off, 64);
        if (lane >= off) s += t;
    }
    if (lane < nb) bsum[lane] = s - v;  // exclusive
}

__global__ void k_scan3(int* __restrict__ rs, const int* __restrict__ bsum) {
    int i = blockIdx.x * blockDim.x + threadIdx.x;
    if (i < N_NODES) rs[i] += bsum[i >> 10];
    if (i == 0) rs[N_NODES] = N_EDGES;
}

__global__ void k_fill2(const int* __restrict__ src, const int* __restrict__ dst,
                        const int* __restrict__ rs, const int* __restrict__ rank,
                        int* __restrict__ col) {
    int e = blockIdx.x * blockDim.x + threadIdx.x;
    if (e < N_EDGES) col[rs[dst[e]] + rank[e]] = src[e];
}

// ---------------- f32 -> bf16 cast ----------------

__global__ void k_cast(const float* __restrict__ x, unsigned short* __restrict__ xb) {
    int i = blockIdx.x * blockDim.x + threadIdx.x;
    if (i >= (N_NODES * D) / 4) return;
    float4 v = reinterpret_cast<const float4*>(x)[i];
    ushort4 o;
    o.x = f2b(v.x); o.y = f2b(v.y); o.z = f2b(v.z); o.w = f2b(v.w);
    reinterpret_cast<ushort4*>(xb)[i] = o;
}

// ---------------- pack weights into MFMA B-fragment order ----------------
// Bp[layer][kstep][cf][lane][i] = W[kstep*32 + 8*(lane>>4) + i][cf*16 + (lane&15)]
// kstep<4 -> w_nbr, else w_root (k offset -128).

__global__ void k_packw(const float* __restrict__ wn0, const float* __restrict__ wr0,
                        const float* __restrict__ wn1, const float* __restrict__ wr1,
                        const float* __restrict__ wn2, const float* __restrict__ wr2,
                        unsigned short* __restrict__ Bp) {
    int t = blockIdx.x * blockDim.x + threadIdx.x;
    if (t >= 3 * 8 * 8 * 64) return;
    int layer = t >> 12;
    int rem = t & 4095;
    int kstep = rem >> 9;
    int cf = (rem >> 6) & 7;
    int lane = t & 63;
    const float* wns[3] = {wn0, wn1, wn2};
    const float* wrs[3] = {wr0, wr1, wr2};
    int kb = kstep * 32 + (lane >> 4) * 8;
    int colv = cf * 16 + (lane & 15);
    const float* W = (kstep < 4) ? wns[layer] : wrs[layer];
    int koff = (kstep < 4) ? kb : kb - 128;
    unsigned short* dstp = Bp + (((layer * 64 + kstep * 8 + cf) * 64 + lane) << 3);
    #pragma unroll
    for (int i = 0; i < 8; ++i) dstp[i] = f2b(W[(koff + i) * D + colv]);
}

// ---------------- mean aggregation: one node per wave ----------------
// Main loop: wave-UNIFORM trip count (niter4 same for all lanes) -> shfl
// sources always active. Remainder/tail: direct col[j] loads (no shfl under
// divergence — that was round 4/5's bug: ds_bpermute from exec-masked lanes).

#define ACCUM(v)                                                      \
    acc0 += bits2f((v).x << 16); acc1 += bits2f((v).x & 0xffff0000u); \
    acc2 += bits2f((v).y << 16); acc3 += bits2f((v).y & 0xffff0000u); \
    acc4 += bits2f((v).z << 16); acc5 += bits2f((v).z & 0xffff0000u); \
    acc6 += bits2f((v).w << 16); acc7 += bits2f((v).w & 0xffff0000u);

__global__ __launch_bounds__(256) void k_agg2(const unsigned short* __restrict__ h,
                                              const int* __restrict__ rs,
                                              const int* __restrict__ col,
                                              unsigned short* __restrict__ mean) {
    const int lane = threadIdx.x & 63;
    const int node = blockIdx.x * 4 + (threadIdx.x >> 6);
    if (node >= N_NODES) return;
    const int j0 = rs[node], j1 = rs[node + 1];
    const int deg = j1 - j0;
    const int q = lane >> 4;      // neighbor slot
    const int d8 = (lane & 15) * 8;

    int myc = (j0 + lane < j1) ? col[j0 + lane] : 0;  // one coalesced load
    const int nfull = deg < 64 ? deg : 64;
    const int niter4 = nfull >> 4;  // wave-uniform

    float acc0 = 0.f, acc1 = 0.f, acc2 = 0.f, acc3 = 0.f;
    float acc4 = 0.f, acc5 = 0.f, acc6 = 0.f, acc7 = 0.f;

    for (int i = 0; i < niter4; ++i) {   // uniform trip count: shfl is safe
        int t = q + (i << 4);
        int c0 = __shfl(myc, t, 64);
        int c1 = __shfl(myc, t + 4, 64);
        int c2 = __shfl(myc, t + 8, 64);
        int c3 = __shfl(myc, t + 12, 64);
        uint4 v0 = *(const uint4*)(h + (size_t)c0 * D + d8);
        uint4 v1 = *(const uint4*)(h + (size_t)c1 * D + d8);
        uint4 v2 = *(const uint4*)(h + (size_t)c2 * D + d8);
        uint4 v3 = *(const uint4*)(h + (size_t)c3 * D + d8);
        ACCUM(v0); ACCUM(v1); ACCUM(v2); ACCUM(v3);
    }
    // remainder + deg>64 tail: direct index loads, no cross-lane ops
    for (int j = j0 + (niter4 << 4) + q; j < j1; j += 4) {
        int c = col[j];
        uint4 v = *(const uint4*)(h + (size_t)c * D + d8);
        ACCUM(v);
    }

    acc0 += __shfl_xor(acc0, 16, 64); acc0 += __shfl_xor(acc0, 32, 64);
    acc1 += __shfl_xor(acc1, 16, 64); acc1 += __shfl_xor(acc1, 32, 64);
    acc2 += __shfl_xor(acc2, 16, 64); acc2 += __shfl_xor(acc2, 32, 64);
    acc3 += __shfl_xor(acc3, 16, 64); acc3 += __shfl_xor(acc3, 32, 64);
    acc4 += __shfl_xor(acc4, 16, 64); acc4 += __shfl_xor(acc4, 32, 64);
    acc5 += __shfl_xor(acc5, 16, 64); acc5 += __shfl_xor(acc5, 32, 64);
    acc6 += __shfl_xor(acc6, 16, 64); acc6 += __shfl_xor(acc6, 32, 64);
    acc7 += __shfl_xor(acc7, 16, 64); acc7 += __shfl_xor(acc7, 32, 64);

    if (lane < 16) {
        float s = 1.0f / (float)(deg > 0 ? deg : 1);
        uint4 o;
        o.x = (unsigned int)f2b(acc0 * s) | ((unsigned int)f2b(acc1 * s) << 16);
        o.y = (unsigned int)f2b(acc2 * s) | ((unsigned int)f2b(acc3 * s) << 16);
        o.z = (unsigned int)f2b(acc4 * s) | ((unsigned int)f2b(acc5 * s) << 16);
        o.w = (unsigned int)f2b(acc6 * s) | ((unsigned int)f2b(acc7 * s) << 16);
        *reinterpret_cast<uint4*>(mean + (size_t)node * D + d8) = o;
    }
}

// ---------------- MFMA GEMM: out = [mean|h] @ [Wn;Wr] + b (+relu / +cls) --
// One wave per 16-row group; full N=128 (8 col-frags); K=256 in 8 steps.

template <int ACT, int CLS>
__global__ __launch_bounds__(256) void k_gemm(
    const unsigned short* __restrict__ Amean, const unsigned short* __restrict__ Ah,
    const unsigned short* __restrict__ Bp, const float* __restrict__ bias,
    unsigned short* __restrict__ outh, const float* __restrict__ wc,
    const float* __restrict__ bc, float* __restrict__ outf) {
    int lane = threadIdx.x & 63;
    int group = blockIdx.x * 4 + (threadIdx.x >> 6);
    if (group >= NGROUPS) return;
    int row0 = group * 16;
    int arow = row0 + (lane & 15);
    int klane = (lane >> 4) * 8;

    f32x4 acc[8];
    #pragma unroll
    for (int i = 0; i < 8; ++i) acc[i] = (f32x4)0.0f;

    const short8* bpv = reinterpret_cast<const short8*>(Bp);
    #pragma unroll
    for (int kstep = 0; kstep < 8; ++kstep) {
        const unsigned short* Asrc = (kstep < 4) ? Amean : Ah;
        int kk = (kstep & 3) * 32 + klane;
        short8 a = *reinterpret_cast<const short8*>(Asrc + (size_t)arow * D + kk);
        #pragma unroll
        for (int cf = 0; cf < 8; ++cf) {
            short8 b = bpv[(kstep * 8 + cf) * 64 + lane];
            acc[cf] = __builtin_amdgcn_mfma_f32_16x16x32_bf16(a, b, acc[cf], 0, 0, 0);
        }
    }

    int rbase = row0 + (lane >> 4) * 4;
    if (CLS) {
        float p0 = 0.f, p1 = 0.f, p2 = 0.f, p3 = 0.f;
        #pragma unroll
        for (int cf = 0; cf < 8; ++cf) {
            int bcol = cf * 16 + (lane & 15);
            float bv = bias[bcol];
            float wcv = wc[bcol];
            p0 += (acc[cf][0] + bv) * wcv;
            p1 += (acc[cf][1] + bv) * wcv;
            p2 += (acc[cf][2] + bv) * wcv;
            p3 += (acc[cf][3] + bv) * wcv;
        }
        #pragma unroll
        for (int m = 1; m < 16; m <<= 1) {
            p0 += __shfl_xor(p0, m, 64);
            p1 += __shfl_xor(p1, m, 64);
            p2 += __shfl_xor(p2, m, 64);
            p3 += __shfl_xor(p3, m, 64);
        }
        if ((lane & 15) == 0) {
            float bcv = bc[0];
            outf[rbase + 0] = p0 + bcv;
            outf[rbase + 1] = p1 + bcv;
            outf[rbase + 2] = p2 + bcv;
            outf[rbase + 3] = p3 + bcv;
        }
    } else {
        #pragma unroll
        for (int cf = 0; cf < 8; ++cf) {
            int bcol = cf * 16 + (lane & 15);
            float bv = bias[bcol];
            #pragma unroll
            for (int i = 0; i < 4; ++i) {
                float v = acc[cf][i] + bv;
                if (ACT) v = fmaxf(v, 0.f);
                outh[(size_t)(rbase + i) * D + bcol] = f2b(v);
            }
        }
    }
}

// ---------------- launch ----------------

extern "C" void kernel_launch(void* const* d_in, const int* in_sizes, int n_in,
                              void* d_out, int out_size, void* d_ws,
                              size_t ws_size, hipStream_t stream) {
    const float* x = (const float*)d_in[0];
    const int* ei = (const int*)d_in[1];
    const int* src = ei;
    const int* dst = ei + N_EDGES;
    const float* wn[3] = {(const float*)d_in[2], (const float*)d_in[5],
                          (const float*)d_in[8]};
    const float* wr[3] = {(const float*)d_in[3], (const float*)d_in[6],
                          (const float*)d_in[9]};
    const float* bs[3] = {(const float*)d_in[4], (const float*)d_in[7],
                          (const float*)d_in[10]};
    const float* wc = (const float*)d_in[11];
    const float* bc = (const float*)d_in[12];
    float* out = (float*)d_out;

    char* ws = (char*)d_ws;
    size_t off = 0;
    auto alloc = [&](size_t bytes) -> void* {
        void* p = (void*)(ws + off);
        off += (bytes + 255) & ~(size_t)255;
        return p;
    };
    // ~45.4 MB total. Three feature buffers rotated as in/mean/out; each
    // write target is dead at write time.
    int* deg = (int*)alloc(N_NODES * 4);
    int* rs = (int*)alloc((N_NODES + 1) * 4);
    int* rank = (int*)alloc(N_EDGES * 4);
    int* bsum = (int*)alloc(64 * 4);
    int* col = (int*)alloc(N_EDGES * 4);
    unsigned short* f0 = (unsigned short*)alloc((size_t)N_NODES * D * 2);
    unsigned short* f1 = (unsigned short*)alloc((size_t)N_NODES * D * 2);
    unsigned short* f2 = (unsigned short*)alloc((size_t)N_NODES * D * 2);
    unsigned short* Bp = (unsigned short*)alloc(3 * 256 * 128 * 2);

    hipMemsetAsync(deg, 0, N_NODES * 4, stream);

    int nb = (N_NODES + 1023) / 1024;
    k_degrank<<<(N_EDGES + 255) / 256, 256, 0, stream>>>(dst, deg, rank);
    k_scan1<<<nb, 1024, 0, stream>>>(deg, rs, bsum);
    k_scan2<<<1, 64, 0, stream>>>(bsum, nb);
    k_scan3<<<(N_NODES + 255) / 256, 256, 0, stream>>>(rs, bsum);
    k_fill2<<<(N_EDGES + 255) / 256, 256, 0, stream>>>(src, dst, rs, rank, col);

    k_cast<<<(N_NODES * D / 4 + 255) / 256, 256, 0, stream>>>(x, f0);
    k_packw<<<48, 256, 0, stream>>>(wn[0], wr[0], wn[1], wr[1], wn[2], wr[2], Bp);

    const int agg_grid = (N_NODES + 3) / 4;
    const int gemm_grid = (NGROUPS + 3) / 4;
    unsigned short* Bp0 = Bp;
    unsigned short* Bp1 = Bp + 256 * 128;
    unsigned short* Bp2 = Bp + 2 * 256 * 128;

    // layer 0: in=f0, mean=f1, out=f2 (relu)
    k_agg2<<<agg_grid, 256, 0, stream>>>(f0, rs, col, f1);
    k_gemm<1, 0><<<gemm_grid, 256, 0, stream>>>(f1, f0, Bp0, bs[0], f2,
                                                nullptr, nullptr, nullptr);
    // layer 1: in=f2, mean=f0, out=f1 (relu)
    k_agg2<<<agg_grid, 256, 0, stream>>>(f2, rs, col, f0);
    k_gemm<1, 0><<<gemm_grid, 256, 0, stream>>>(f0, f2, Bp1, bs[1], f1,
                                                nullptr, nullptr, nullptr);
    // layer 2 + classifier: in=f1, mean=f2, out=d_out (f32)
    k_agg2<<<agg_grid, 256, 0, stream>>>(f1, rs, col, f2);
    k_gemm<0, 1><<<gemm_grid, 256, 0, stream>>>(f2, f1, Bp2, bs[2], nullptr,
                                                wc, bc, out);
}